// Round 8
// baseline (287.675 us; speedup 1.0000x reference)
//
#include <hip/hip_runtime.h>
#include <hip/hip_bf16.h>
#include <math.h>

// EpisodicMemory fused pipeline for MI355X (gfx950).
// B=16384, HID=1024, SLOTS=64, KD=32.
// Dominant cost: ONE [16384,2048]x[2048,2048] bf16 MFMA GEMM (gate/out weights
// row-interleaved in 16-col groups) with fused sigmoid/GELU/blend epilogue.
// k_gemm round 8: m97-replica occupancy-first structure. 128x128 tile, BK=64,
// 256 threads (4 waves, 2x2), single 32KB LDS buffer, plain
// stage -> __syncthreads -> compute -> __syncthreads loop, both-sides chunk
// swizzle (0 bank conflicts), __launch_bounds__(256,4) for 4 blocks/CU ->
// 16 waves/CU of INDEPENDENT blocks (inter-block overlap hides the barrier
// drain; m114/m97 mechanism), bijective XCD-chunked block mapping.

typedef float    f32x4 __attribute__((ext_vector_type(4)));
typedef short    s16x8 __attribute__((ext_vector_type(8)));
typedef unsigned short u16;
typedef unsigned short u16x8 __attribute__((ext_vector_type(8)));

#define MFMA_BF16(a,b,c) __builtin_amdgcn_mfma_f32_16x16x32_bf16((a),(b),(c),0,0,0)

__device__ __forceinline__ void async16(void* lds, const void* g) {
  __builtin_amdgcn_global_load_lds((const __attribute__((address_space(1))) void*)g,
                                   (__attribute__((address_space(3))) void*)lds, 16, 0, 0);
}

__device__ __forceinline__ u16 f2bf(float f) {
  unsigned u = __float_as_uint(f);
  u += 0x7fffu + ((u >> 16) & 1u);   // RNE
  return (u16)(u >> 16);
}
__device__ __forceinline__ float bf2f(u16 h) {
  return __uint_as_float(((unsigned)h) << 16);
}

// ---------------- K0: per-slot prep (keys_with_pos normalized, bias) --------
__global__ void k_prep(const float* __restrict__ mem_keys, const float* __restrict__ pos_table,
                       const int* __restrict__ slot_order, const float* __restrict__ mem_age,
                       const float* __restrict__ mem_conf,
                       float* __restrict__ kwp /*[64][33] padded*/, float* __restrict__ biasv) {
  int s = threadIdx.x;            // 64 threads = 1 wave
  float age  = mem_age[s];
  float freq = fmaxf(age, 1.0f);
  float fm = freq;
  #pragma unroll
  for (int o = 32; o; o >>= 1) fm = fmaxf(fm, __shfl_xor(fm, o));
  float freq_norm = logf(freq + 1.0f) / (logf(fm + 2.0f) + 1e-8f);
  float recency = expf(-age * (1.0f/200.0f));
  biasv[s] = 0.2f*recency + 0.15f*freq_norm + 0.1f*mem_conf[s] + 0.08f;

  int idx = slot_order[s] & 63;   // % SLOTS (values are arange, nonneg)
  float k[32]; float ss = 0.f;
  #pragma unroll
  for (int d = 0; d < 32; d++) {
    float v = mem_keys[s*32+d] + 0.1f*pos_table[idx*32+d];
    k[d] = v; ss += v*v;
  }
  float inv = 1.0f / fmaxf(sqrtf(ss), 1e-12f);
  #pragma unroll
  for (int d = 0; d < 32; d++) kwp[s*33+d] = k[d]*inv;
}

// ---------------- K1: fp32 -> bf16 conversions ------------------------------
// Weights go to Wcat [2048][2048]: row p = g*32 + h*16 + c holds
// (h==0 ? gate_w : out_w) row (g*16+c).
__global__ __launch_bounds__(256) void k_convert(
    const float* __restrict__ x, const float* __restrict__ gate_w,
    const float* __restrict__ out_w, const float* __restrict__ key_w,
    const float* __restrict__ mem_vals,
    u16* __restrict__ A, u16* __restrict__ Wcat,
    u16* __restrict__ Wk, u16* __restrict__ Vals) {
  const int NX = 4194304, NW = 524288, NK = 8192, NV = 16384;  // float4 groups
  const int total = NX + 2*NW + NK + NV;
  for (int g = blockIdx.x*256 + threadIdx.x; g < total; g += gridDim.x*256) {
    float4 v; u16* dst;
    if (g < NX) {                       // x -> combined[:, 0:1024]
      v = ((const float4*)x)[g];
      int r = g >> 8, c4 = g & 255;
      dst = A + ((size_t)r*2048 + c4*4);
    } else if (g < NX+NW) {             // gate_w -> Wcat interleaved
      int t = g-NX; v = ((const float4*)gate_w)[t];
      int row = t >> 9, grp = t & 511;
      int p = ((row>>4)<<5) + (row&15);
      dst = Wcat + ((size_t)p*2048 + grp*4);
    } else if (g < NX+2*NW) {           // out_w -> Wcat interleaved (+16)
      int t = g-NX-NW; v = ((const float4*)out_w)[t];
      int row = t >> 9, grp = t & 511;
      int p = ((row>>4)<<5) + 16 + (row&15);
      dst = Wcat + ((size_t)p*2048 + grp*4);
    } else if (g < NX+2*NW+NK) {
      int t = g-NX-2*NW; v = ((const float4*)key_w)[t];   dst = Wk + (size_t)t*4;
    } else {
      int t = g-NX-2*NW-NK; v = ((const float4*)mem_vals)[t]; dst = Vals + (size_t)t*4;
    }
    ushort4 o; o.x=f2bf(v.x); o.y=f2bf(v.y); o.z=f2bf(v.z); o.w=f2bf(v.w);
    *(ushort4*)dst = o;
  }
}

// ---------------- K2a: qk = x @ key_w^T  (thin MFMA GEMM) -------------------
__global__ __launch_bounds__(256) void k_qk(const u16* __restrict__ A, const u16* __restrict__ Wk,
                                            float* __restrict__ qk) {
  __shared__ __align__(16) u16 sA[64*64];
  __shared__ __align__(16) u16 sB[32*64];
  int tid = threadIdx.x, lane = tid & 63, w = tid >> 6;
  int r0 = blockIdx.x * 64;
  f32x4 acc[2] = { {0.f,0.f,0.f,0.f}, {0.f,0.f,0.f,0.f} };
  for (int k0 = 0; k0 < 1024; k0 += 64) {
    const char* Ab = (const char*)A + ((size_t)r0*2048 + k0)*2;   // A row stride 4096 B
    #pragma unroll
    for (int i = 0; i < 2; i++) {
      int cidx = tid + i*256;                  // 512 chunks of 16 B
      async16((char*)sA + cidx*16, Ab + (size_t)(cidx>>3)*4096 + (size_t)(cidx&7)*16);
    }
    { const char* Bb = (const char*)Wk + (size_t)k0*2;            // Wk row stride 2048 B
      async16((char*)sB + tid*16, Bb + (size_t)(tid>>3)*2048 + (size_t)(tid&7)*16); }
    __syncthreads();
    #pragma unroll
    for (int kk = 0; kk < 2; kk++) {
      int kb = kk*32 + (lane>>4)*8;
      s16x8 a  = *(const s16x8*)&sA[(w*16 + (lane&15))*64 + kb];
      s16x8 b0 = *(const s16x8*)&sB[(lane&15)*64 + kb];
      s16x8 b1 = *(const s16x8*)&sB[((lane&15)+16)*64 + kb];
      acc[0] = MFMA_BF16(a, b0, acc[0]);
      acc[1] = MFMA_BF16(a, b1, acc[1]);
    }
    __syncthreads();
  }
  int rr = (lane>>4)*4, cc = lane&15;
  #pragma unroll
  for (int n = 0; n < 2; n++)
    #pragma unroll
    for (int i = 0; i < 4; i++)
      qk[(size_t)(r0 + w*16 + rr + i)*32 + n*16 + cc] = acc[n][i];
}

// ---------------- K2b: softmax over slots + retrieved = attn @ mem_vals -----
__global__ __launch_bounds__(256) void k_retr(const float* __restrict__ qk,
                                              const float* __restrict__ kwp,
                                              const float* __restrict__ biasv,
                                              const u16* __restrict__ Vals,
                                              u16* __restrict__ A) {
  __shared__ float sK[64*33];
  __shared__ float sBias[64];
  __shared__ float sQn[16*32];
  __shared__ float sAttn[16*64];
  int tid = threadIdx.x, lane = tid & 63, w = tid >> 6;
  int row0 = blockIdx.x * 16;
  for (int i = tid; i < 64*33; i += 256) sK[i] = kwp[i];
  if (tid < 64) sBias[tid] = biasv[tid];
  __syncthreads();

  int d = lane & 31;
  for (int j = 0; j < 4; j++) {
    int rl = w*4 + j;
    float v = qk[(size_t)(row0+rl)*32 + d];
    float sq = v*v;
    #pragma unroll
    for (int o = 16; o; o >>= 1) sq += __shfl_xor(sq, o);   // 32-lane group sum
    float qn = v / fmaxf(sqrtf(sq), 1e-12f);
    if (lane < 32) sQn[rl*32 + d] = qn;
    float accs = 0.f;
    #pragma unroll
    for (int dd = 0; dd < 32; dd++) accs += sK[lane*33+dd] * sQn[rl*32+dd];
    float sim = accs * 0.17677669529663687f;   // 1/sqrt(32)
    float sal = fminf(fmaxf(0.45f*sim + sBias[lane], 0.0f), 1.0f);
    float mx = sal;
    #pragma unroll
    for (int o = 32; o; o >>= 1) mx = fmaxf(mx, __shfl_xor(mx, o));
    float e = expf(sal - mx);
    float sm = e;
    #pragma unroll
    for (int o = 32; o; o >>= 1) sm += __shfl_xor(sm, o);
    sAttn[rl*64 + lane] = e / sm;
  }
  __syncthreads();

  float acc[4][16];
  #pragma unroll
  for (int j = 0; j < 4; j++)
    #pragma unroll
    for (int i = 0; i < 16; i++) acc[j][i] = 0.f;
  const u16* vp = Vals + lane*16;
  for (int s = 0; s < 64; s++) {
    s16x8 v0 = *(const s16x8*)(vp + (size_t)s*1024);
    s16x8 v1 = *(const s16x8*)(vp + (size_t)s*1024 + 8);
    float vf[16];
    #pragma unroll
    for (int i = 0; i < 8; i++) { vf[i] = bf2f((u16)v0[i]); vf[8+i] = bf2f((u16)v1[i]); }
    #pragma unroll
    for (int j = 0; j < 4; j++) {
      float a = sAttn[(w*4+j)*64 + s];
      #pragma unroll
      for (int i = 0; i < 16; i++) acc[j][i] += a * vf[i];
    }
  }
  #pragma unroll
  for (int j = 0; j < 4; j++) {
    int r = row0 + w*4 + j;
    u16x8 o0, o1;
    #pragma unroll
    for (int i = 0; i < 8; i++) { o0[i] = f2bf(acc[j][i]); o1[i] = f2bf(acc[j][8+i]); }
    u16* dst = A + (size_t)r*2048 + 1024 + lane*16;   // combined[:, 1024:2048]
    *(u16x8*)dst = o0;
    *(u16x8*)(dst + 8) = o1;
  }
}

// ---------------- K3: single interleaved GEMM + fused epilogue --------------
// C = combined[16384,2048] @ Wcat[2048,2048]^T.
// 128x128 tile, 4 waves (2x2, wave=64x64), BK=64, single 32KB LDS buffer,
// plain 2-barrier loop; overlap comes from 4 INDEPENDENT blocks/CU.
__global__ __launch_bounds__(256, 4) void k_gemm(
    const u16* __restrict__ A, const u16* __restrict__ Wcat,
    const float* __restrict__ out_b, const float* __restrict__ gate_b,
    float* __restrict__ y) {
  __shared__ __align__(16) u16 sA[8192];   // 128 rows x 64 cols (swizzled)
  __shared__ __align__(16) u16 sB[8192];

  const int tid = threadIdx.x, lane = tid & 63, w = tid >> 6;
  const int ln15 = lane & 15, hi = lane >> 4, p7 = ln15 & 7;
  const int wr = w >> 1, wc = w & 1;

  // bijective XCD-chunked mapping: 2048 blocks, 256/XCD; each XCD holds 2
  // weight panels (2 x 512KB in its 4MB L2), sweeping all 128 rowblks each.
  const int b = blockIdx.x;
  const int xcd = b & 7, idx = b >> 3;
  const int colblk = xcd * 2 + (idx >> 7);   // 0..15
  const int rowblk = idx & 127;              // 0..127
  const size_t r0 = (size_t)rowblk * 128;
  const size_t c0 = (size_t)colblk * 128;

  const u16* gA = A    + r0 * 2048;
  const u16* gB = Wcat + c0 * 2048;

  // staging: 1024 chunks of 16B per tile, 4/thread. physical chunk pc of
  // row r holds logical chunk pc ^ (r&7)  (inverse swizzle on global source).
  int off[4];
  #pragma unroll
  for (int j = 0; j < 4; j++) {
    int c = tid + j * 256;
    int row = c >> 3, pc = c & 7;
    off[j] = row * 2048 + ((pc ^ (row & 7)) << 3);
  }

  // ds_read: logical chunk lc = kk*4+hi -> physical lc ^ (row&7), row&7 = p7
  const int ck0 = (hi ^ p7) * 8;          // kk=0
  const int ck1 = ((4 | hi) ^ p7) * 8;    // kk=1
  const int arow = (wr*64 + ln15) * 64;   // + m*1024
  const int brow = (wc*64 + ln15) * 64;   // + n*1024

  f32x4 acc[4][4];
  #pragma unroll
  for (int m = 0; m < 4; m++)
    #pragma unroll
    for (int n = 0; n < 4; n++) acc[m][n] = {0.f, 0.f, 0.f, 0.f};

  for (int kt = 0; kt < 32; ++kt) {
    const int ko = kt * 64;
    #pragma unroll
    for (int j = 0; j < 4; j++) {
      async16(&sA[(tid + j*256) * 8], gA + off[j] + ko);
      async16(&sB[(tid + j*256) * 8], gB + off[j] + ko);
    }
    __syncthreads();   // drains vmcnt(0): staged tile visible to all waves
    #pragma unroll
    for (int kk = 0; kk < 2; kk++) {
      const int ck = kk ? ck1 : ck0;
      s16x8 af[4], bfr[4];
      #pragma unroll
      for (int m = 0; m < 4; m++) af[m]  = *(const s16x8*)&sA[arow + m*1024 + ck];
      #pragma unroll
      for (int n = 0; n < 4; n++) bfr[n] = *(const s16x8*)&sB[brow + n*1024 + ck];
      #pragma unroll
      for (int m = 0; m < 4; m++)
        #pragma unroll
        for (int n = 0; n < 4; n++)
          acc[m][n] = MFMA_BF16(af[m], bfr[n], acc[m][n]);
    }
    __syncthreads();   // tile fully consumed before next stage overwrites
  }

  // epilogue: Wcat rows c0+wc*64+n*16+c -> (n&1 ? out : gate), ocol =
  // colblk*64 + wc*32 + (n>>1)*16 + ln15. y pre-LN; x read from A bf16 left.
  #pragma unroll
  for (int s = 0; s < 2; s++) {
    int ocol = colblk*64 + wc*32 + s*16 + ln15;
    float gbv = gate_b[ocol], obv = out_b[ocol];
    #pragma unroll
    for (int m = 0; m < 4; m++) {
      #pragma unroll
      for (int i = 0; i < 4; i++) {
        size_t r = r0 + wr*64 + m*16 + hi*4 + i;
        float gg = acc[m][s*2+0][i] + gbv;
        float go = acc[m][s*2+1][i] + obv;
        float h  = 0.5f*go*(1.0f + erff(go*0.70710678118654752f));  // exact gelu
        float sg = 1.0f/(1.0f + __expf(-gg));
        float rv = bf2f(A[r*2048 + 1024 + ocol]);
        float xv = bf2f(A[r*2048 + ocol]);
        y[r*1024 + ocol] = h + sg*rv + (1.0f - sg)*xv;
      }
    }
  }
}

// ---------------- K4: LayerNorm in place (wave per row) ---------------------
__global__ __launch_bounds__(256) void k_ln(float* __restrict__ y, const float* __restrict__ g,
                                            const float* __restrict__ b) {
  int row  = blockIdx.x*4 + (threadIdx.x >> 6);
  int lane = threadIdx.x & 63;
  float4* p = (float4*)(y + (size_t)row*1024);
  float4 v[4];
  #pragma unroll
  for (int i = 0; i < 4; i++) v[i] = p[lane + 64*i];
  float s = 0.f;
  #pragma unroll
  for (int i = 0; i < 4; i++) s += v[i].x + v[i].y + v[i].z + v[i].w;
  #pragma unroll
  for (int o = 32; o; o >>= 1) s += __shfl_xor(s, o);
  float mu = s * (1.0f/1024.0f);
  float vs = 0.f;
  #pragma unroll
  for (int i = 0; i < 4; i++) {
    float d0 = v[i].x-mu, d1 = v[i].y-mu, d2 = v[i].z-mu, d3 = v[i].w-mu;
    vs += d0*d0 + d1*d1 + d2*d2 + d3*d3;
  }
  #pragma unroll
  for (int o = 32; o; o >>= 1) vs += __shfl_xor(vs, o);
  float inv = 1.0f / sqrtf(vs*(1.0f/1024.0f) + 1e-5f);
  const float4* gp = (const float4*)g;
  const float4* bp = (const float4*)b;
  #pragma unroll
  for (int i = 0; i < 4; i++) {
    float4 gv = gp[lane+64*i], bv = bp[lane+64*i], o4;
    o4.x = (v[i].x-mu)*inv*gv.x + bv.x;
    o4.y = (v[i].y-mu)*inv*gv.y + bv.y;
    o4.z = (v[i].z-mu)*inv*gv.z + bv.z;
    o4.w = (v[i].w-mu)*inv*gv.w + bv.w;
    p[lane + 64*i] = o4;
  }
}

// ---------------- launch ----------------------------------------------------
extern "C" void kernel_launch(void* const* d_in, const int* in_sizes, int n_in,
                              void* d_out, int out_size, void* d_ws, size_t ws_size,
                              hipStream_t stream) {
  const float* x         = (const float*)d_in[0];
  const float* key_w     = (const float*)d_in[1];
  const float* out_w     = (const float*)d_in[2];
  const float* out_b     = (const float*)d_in[3];
  const float* gate_w    = (const float*)d_in[4];
  const float* gate_b    = (const float*)d_in[5];
  const float* ln_g      = (const float*)d_in[6];
  const float* ln_b      = (const float*)d_in[7];
  const float* pos_table = (const float*)d_in[8];
  const float* mem_keys  = (const float*)d_in[9];
  const float* mem_vals  = (const float*)d_in[10];
  const float* mem_age   = (const float*)d_in[11];
  const float* mem_conf  = (const float*)d_in[12];
  const int*   slot_order= (const int*)d_in[13];

  char* ws = (char*)d_ws;
  u16*   A    = (u16*)(ws + 0);            // combined bf16 [16384][2048]  64 MB
  u16*   Wcat = (u16*)(ws + 67108864);     // interleaved weights [2048][2048] 8 MB
  u16*   Wk   = (u16*)(ws + 75497472);     // key_w  bf16 [32][1024]       64 KB
  u16*   Vals = (u16*)(ws + 75563008);     // mem_vals bf16 [64][1024]    128 KB
  float* kwp  = (float*)(ws + 75694080);   // keys_with_pos [64][33]     8448 B
  float* biasv= (float*)(ws + 75702528);   // salience bias [64]
  float* qk   = (float*)(ws + 75702784);   // qk [16384][32] f32            2 MB
  float* y    = (float*)d_out;

  hipLaunchKernelGGL(k_prep,    dim3(1),    dim3(64),  0, stream,
                     mem_keys, pos_table, slot_order, mem_age, mem_conf, kwp, biasv);
  hipLaunchKernelGGL(k_convert, dim3(8192), dim3(256), 0, stream,
                     x, gate_w, out_w, key_w, mem_vals, A, Wcat, Wk, Vals);
  hipLaunchKernelGGL(k_qk,      dim3(256),  dim3(256), 0, stream, A, Wk, qk);
  hipLaunchKernelGGL(k_retr,    dim3(1024), dim3(256), 0, stream, qk, kwp, biasv, Vals, A);
  hipLaunchKernelGGL(k_gemm,    dim3(2048), dim3(256), 0, stream,
                     A, Wcat, out_b, gate_b, y);
  hipLaunchKernelGGL(k_ln,      dim3(4096), dim3(256), 0, stream, y, ln_g, ln_b);
}